// Round 5
// baseline (1449.606 us; speedup 1.0000x reference)
//
#include <hip/hip_runtime.h>
#include <hip/hip_bf16.h>

#define B_   32
#define T_   128
#define H_   700
#define HP2  768          // h K-pad for 16x16x32 MFMA tiling (4 waves x 6 tiles x 32)
#define E_   100
#define G3   2100
#define V_   32000
#define DY_  200
#define DZ_  500
#define KP   704          // g / Wb K-pad for projection GEMM
#define NBLK 175
#define JW   4
#define FSTR 16
#define BT   4096         // B_*T_

typedef __attribute__((ext_vector_type(8))) short bf16x8;
typedef __attribute__((ext_vector_type(4))) float f32x4;

__device__ __forceinline__ unsigned ld_flag(const unsigned* p) {
    return __hip_atomic_load(p, __ATOMIC_RELAXED, __HIP_MEMORY_SCOPE_AGENT);
}
__device__ __forceinline__ void st_flag(unsigned* p, unsigned v) {
    __hip_atomic_store(p, v, __ATOMIC_RELAXED, __HIP_MEMORY_SCOPE_AGENT);
}
__device__ __forceinline__ unsigned long long ld_h8(const unsigned long long* p) {
    return __hip_atomic_load(p, __ATOMIC_RELAXED, __HIP_MEMORY_SCOPE_AGENT);
}
__device__ __forceinline__ void st_h8(unsigned long long* p, unsigned long long v) {
    __hip_atomic_store(p, v, __ATOMIC_RELAXED, __HIP_MEMORY_SCOPE_AGENT);
}
// split fp32 into bf16 hi + bf16 lo (residual); hi+lo ~ 16-bit-mantissa accurate
__device__ __forceinline__ void split_bf(float v, short& hi, short& lo) {
    __hip_bfloat16 h = __float2bfloat16(v);
    float r = v - __bfloat162float(h);
    __hip_bfloat16 l = __float2bfloat16(r);
    hi = *reinterpret_cast<short*>(&h);
    lo = *reinterpret_cast<short*>(&l);
}

// ---------------- proj_W [700][32000] fp32 -> Wb [32000][704] bf16 ----------------
__global__ __launch_bounds__(256)
void wconv_kernel(const float* __restrict__ W, __hip_bfloat16* __restrict__ Wb) {
    __shared__ float tile[32][33];
    const int n0 = blockIdx.x * 32, k0 = blockIdx.y * 32;
    const int tx = threadIdx.x, ty = threadIdx.y;
    #pragma unroll
    for (int i = 0; i < 4; ++i) {
        int k = k0 + ty + 8 * i;
        float v = (k < H_) ? W[(size_t)k * V_ + n0 + tx] : 0.0f;
        tile[ty + 8 * i][tx] = v;
    }
    __syncthreads();
    #pragma unroll
    for (int i = 0; i < 4; ++i) {
        int nn = ty + 8 * i;
        Wb[(size_t)(n0 + nn) * KP + k0 + tx] = __float2bfloat16(tile[tx][nn]);
    }
}

// ---------------- xp[b*T+t][2100] = emb[dec[b][t]] @ gru1_k + gru1_b[0]; zero g pads ----------------
__global__ __launch_bounds__(256)
void xp_kernel(const int* __restrict__ di, const float* __restrict__ emb,
               const float* __restrict__ gk, const float* __restrict__ gb,
               float* __restrict__ xp, __hip_bfloat16* __restrict__ g_out) {
    __shared__ float xl[E_];
    const int row = blockIdx.x;
    const int tid = threadIdx.x;
    if (tid < E_) xl[tid] = emb[(size_t)di[row] * E_ + tid];
    if (tid < KP - H_) g_out[(size_t)row * KP + H_ + tid] = __float2bfloat16(0.0f);
    __syncthreads();
    for (int j4 = tid; j4 < G3 / 4; j4 += 256) {
        int j = j4 * 4;
        float4 a = *(const float4*)&gb[j];
        #pragma unroll 4
        for (int k = 0; k < E_; ++k) {
            float xv = xl[k];
            float4 wv = *(const float4*)&gk[(size_t)k * G3 + j];
            a.x += xv * wv.x; a.y += xv * wv.y; a.z += xv * wv.z; a.w += xv * wv.w;
        }
        *(float4*)&xp[(size_t)row * G3 + j] = a;
    }
}

// ---------------- xp[bt][c] -> xp_t[c][t*32+b] ----------------
__global__ __launch_bounds__(256)
void xpt_kernel(const float* __restrict__ xp, float* __restrict__ xpt) {
    __shared__ float tl[32][33];
    const int c0 = blockIdx.x * 32, t = blockIdx.y;
    const int tx = threadIdx.x, ty = threadIdx.y;
    #pragma unroll
    for (int i = 0; i < 4; ++i) {
        int b = ty + 8 * i, c = c0 + tx;
        tl[b][tx] = (c < G3) ? xp[(size_t)(b * T_ + t) * G3 + c] : 0.0f;
    }
    __syncthreads();
    #pragma unroll
    for (int i = 0; i < 4; ++i) {
        int cc = ty + 8 * i;
        if (c0 + cc < G3)
            xpt[(size_t)(c0 + cc) * BT + t * 32 + tx] = tl[tx][cc];
    }
}

// ---------------- mask[b][t][j] -> mask_t[j][t*32+b] (bf16; mask in {0,2} exact) ----------------
__global__ __launch_bounds__(256)
void maskt_kernel(const float* __restrict__ mask, __hip_bfloat16* __restrict__ mkt) {
    __shared__ float tl[32][33];
    const int j0 = blockIdx.x * 32, t = blockIdx.y;
    const int tx = threadIdx.x, ty = threadIdx.y;
    #pragma unroll
    for (int i = 0; i < 4; ++i) {
        int b = ty + 8 * i, j = j0 + tx;
        tl[b][tx] = (j < H_) ? mask[(size_t)(b * T_ + t) * H_ + j] : 0.0f;
    }
    __syncthreads();
    #pragma unroll
    for (int i = 0; i < 4; ++i) {
        int cc = ty + 8 * i;
        if (j0 + cc < H_)
            mkt[(size_t)(j0 + cc) * BT + t * 32 + tx] = __float2bfloat16(tl[tx][cc]);
    }
}

// ---------------- persistent GRU, MFMA hi/lo recurrence, pre-split h planes ----------------
// 175 blocks x 256 threads (4 waves). Block owns 4 gate j's (12 rk cols -> 16-col B tile).
// h is exchanged as TWO bf16 planes (hi + lo residual), split ONCE by the producer.
// Consumer 8B coherent loads ARE fragment halves: no split/cvt VALU on the pull path.
// Pull is a 3-deep statically-rotated chunk pipeline (16 loads in flight).
__global__ __launch_bounds__(256, 1)
void gru_kernel(const float* __restrict__ labels, const float* __restrict__ zin,
                const float* __restrict__ W1, const float* __restrict__ b1,
                const float* __restrict__ xpt, const __hip_bfloat16* __restrict__ mkt,
                const float* __restrict__ rk, const float* __restrict__ gb,
                unsigned short* __restrict__ hhi, unsigned short* __restrict__ hlo,
                __hip_bfloat16* __restrict__ g_out, unsigned* __restrict__ flags) {
    __shared__ float part2[4 * 2 * 16 * 17];   // [w][m][row][col] pad17
    __shared__ float xb_z[128], xb_r[128], xb_h[128], xb_m[128];
    __shared__ alignas(8) short smhi[128], smlo[128];

    const int tid = threadIdx.x;
    const int blk = blockIdx.x;
    const int j0  = blk * JW;
    const int wv = tid >> 6, lane = tid & 63, lr = lane & 15, lkg = lane >> 4;

    // rk B-frags in registers, hi/lo
    bf16x8 rkb_hi[6], rkb_lo[6];
    const int gcol = (lr < 12) ? ((lr >> 2) * H_ + j0 + (lr & 3)) : 0;
    #pragma unroll
    for (int t = 0; t < 6; ++t) {
        #pragma unroll
        for (int i = 0; i < 8; ++i) {
            int k = wv * 192 + t * 32 + lkg * 8 + i;
            float v = (lr < 12 && k < H_) ? rk[(size_t)k * G3 + gcol] : 0.0f;
            short hi, lo; split_bf(v, hi, lo);
            rkb_hi[t][i] = hi; rkb_lo[t][i] = lo;
        }
    }

    // h0 init; own h carried in register
    float hold = 0.0f;
    if (tid < 128) {
        int b = tid >> 2, jj = tid & 3, j = j0 + jj;
        float v = (j < DY_) ? labels[b] * W1[j] + b1[j] : zin[b * DZ_ + (j - DY_)];
        hold = v;
        short hi, lo; split_bf(v, hi, lo);
        smhi[tid] = hi; smlo[tid] = lo;
    }
    if (blk == 0) {  // zero K-pads [700,768) of both parities, both planes
        for (int e = tid; e < 2176; e += 256) {
            int pl = e / 1088, r = e % 1088;
            int par = r / 544, rr = r % 544;
            int b = rr / 17, q = rr % 17;
            unsigned long long* base = (unsigned long long*)(pl ? hlo : hhi);
            st_h8(base + par * 6144 + b * 192 + 175 + q, 0ull);
        }
    }
    float bz = 0.f, brr = 0.f, bh = 0.f;
    if (tid < 128) {
        int j = j0 + (tid & 3);
        bz = gb[G3 + j]; brr = gb[G3 + H_ + j]; bh = gb[G3 + 2 * H_ + j];
    }
    __syncthreads();
    if (tid < 32)
        st_h8((unsigned long long*)(hhi + (size_t)tid * HP2 + j0),
              *(const unsigned long long*)&smhi[tid * 4]);
    else if (tid < 64) {
        int b = tid - 32;
        st_h8((unsigned long long*)(hlo + (size_t)b * HP2 + j0),
              *(const unsigned long long*)&smlo[b * 4]);
    }
    __syncthreads();                       // drains vmcnt: h0 + pad stores complete
    if (tid == 0) st_flag(&flags[blk * FSTR], 1u);

    const int i0 = lr * 192 + wv * 48 + lkg * 2;   // u64 index: row lr, wave k-range
    const int i1 = i0 + 16 * 192;                  // row 16+lr

    struct Chunk { unsigned long long d[8]; };
    union FragU { unsigned long long d[2]; bf16x8 v; };

    for (int step = 0; step < T_; ++step) {
        const int cur = step & 1, nxt = cur ^ 1;
        const unsigned long long* phz =
            (const unsigned long long*)(hhi + (size_t)cur * B_ * HP2);
        const unsigned long long* plz =
            (const unsigned long long*)(hlo + (size_t)cur * B_ * HP2);

        // phase 1: prefetch x/mask (cached loads; overlap the poll)
        if (tid < 128) {
            int b = tid & 31, jl = tid >> 5;
            int jc = j0 + jl;
            xb_z[tid] = xpt[(size_t)(0 * H_ + jc) * BT + step * 32 + b];
            xb_r[tid] = xpt[(size_t)(1 * H_ + jc) * BT + step * 32 + b];
            xb_h[tid] = xpt[(size_t)(2 * H_ + jc) * BT + step * 32 + b];
            xb_m[tid] = __bfloat162float(mkt[(size_t)jc * BT + step * 32 + b]);
        }
        // phase 2: wait for all blocks' h_step
        if (tid < NBLK) {
            while (ld_flag(&flags[tid * FSTR]) < (unsigned)(step + 1))
                __builtin_amdgcn_s_sleep(1);
        }
        __syncthreads();

        // phase 3+4: 3-deep pipelined pull + MFMA (all indices static)
        f32x4 acc0 = (f32x4){0.f,0.f,0.f,0.f};
        f32x4 acc1 = (f32x4){0.f,0.f,0.f,0.f};
        Chunk c0, c1, c2;

#define LOADC(T, C) do { \
        (C).d[0] = ld_h8(phz + i0 + (T) * 8); \
        (C).d[1] = ld_h8(phz + i0 + (T) * 8 + 1); \
        (C).d[2] = ld_h8(plz + i0 + (T) * 8); \
        (C).d[3] = ld_h8(plz + i0 + (T) * 8 + 1); \
        (C).d[4] = ld_h8(phz + i1 + (T) * 8); \
        (C).d[5] = ld_h8(phz + i1 + (T) * 8 + 1); \
        (C).d[6] = ld_h8(plz + i1 + (T) * 8); \
        (C).d[7] = ld_h8(plz + i1 + (T) * 8 + 1); \
    } while (0)
#define PROCC(T, C) do { \
        FragU fh0, fl0, fh1, fl1; \
        fh0.d[0] = (C).d[0]; fh0.d[1] = (C).d[1]; \
        fl0.d[0] = (C).d[2]; fl0.d[1] = (C).d[3]; \
        fh1.d[0] = (C).d[4]; fh1.d[1] = (C).d[5]; \
        fl1.d[0] = (C).d[6]; fl1.d[1] = (C).d[7]; \
        acc0 = __builtin_amdgcn_mfma_f32_16x16x32_bf16(fh0.v, rkb_hi[T], acc0, 0, 0, 0); \
        acc0 = __builtin_amdgcn_mfma_f32_16x16x32_bf16(fh0.v, rkb_lo[T], acc0, 0, 0, 0); \
        acc0 = __builtin_amdgcn_mfma_f32_16x16x32_bf16(fl0.v, rkb_hi[T], acc0, 0, 0, 0); \
        acc1 = __builtin_amdgcn_mfma_f32_16x16x32_bf16(fh1.v, rkb_hi[T], acc1, 0, 0, 0); \
        acc1 = __builtin_amdgcn_mfma_f32_16x16x32_bf16(fh1.v, rkb_lo[T], acc1, 0, 0, 0); \
        acc1 = __builtin_amdgcn_mfma_f32_16x16x32_bf16(fl1.v, rkb_hi[T], acc1, 0, 0, 0); \
    } while (0)

        LOADC(0, c0); LOADC(1, c1);
        LOADC(2, c2); PROCC(0, c0);
        LOADC(3, c0); PROCC(1, c1);
        LOADC(4, c1); PROCC(2, c2);
        LOADC(5, c2); PROCC(3, c0);
        PROCC(4, c1); PROCC(5, c2);
#undef LOADC
#undef PROCC

        // per-wave partials (C layout: col=lane&15, row=(lane>>4)*4+r)
        #pragma unroll
        for (int r = 0; r < 4; ++r) {
            part2[((wv * 2 + 0) * 16 + lkg * 4 + r) * 17 + lr] = acc0[r];
            part2[((wv * 2 + 1) * 16 + lkg * 4 + r) * 17 + lr] = acc1[r];
        }
        __syncthreads();

        // gates
        if (tid < 128) {
            int b = tid >> 2, jj = tid & 3, j = j0 + jj;
            int m = b >> 4, row = b & 15;
            float hpz = bz, hpr = brr, hph = bh;
            #pragma unroll
            for (int w = 0; w < 4; ++w) {
                int base = ((w * 2 + m) * 16 + row) * 17;
                hpz += part2[base + jj];
                hpr += part2[base + 4 + jj];
                hph += part2[base + 8 + jj];
            }
            int xi = jj * 32 + b;
            float xz = xb_z[xi], xr = xb_r[xi], xh = xb_h[xi], mv = xb_m[xi];
            float zg = 1.0f / (1.0f + expf(-(xz + hpz)));
            float rg = 1.0f / (1.0f + expf(-(xr + hpr)));
            float hh = tanhf(xh + rg * hph);
            float hn = zg * hold + (1.0f - zg) * hh;
            hold = hn;
            short hi, lo; split_bf(hn, hi, lo);
            smhi[tid] = hi; smlo[tid] = lo;
            g_out[(size_t)(b * T_ + step) * KP + j] = __float2bfloat16(hn * mv);
        }
        __syncthreads();
        if (tid < 32)
            st_h8((unsigned long long*)(hhi + (size_t)nxt * B_ * HP2 + (size_t)tid * HP2 + j0),
                  *(const unsigned long long*)&smhi[tid * 4]);
        else if (tid < 64) {
            int b = tid - 32;
            st_h8((unsigned long long*)(hlo + (size_t)nxt * B_ * HP2 + (size_t)b * HP2 + j0),
                  *(const unsigned long long*)&smlo[b * 4]);
        }
        __syncthreads();                   // drains vmcnt: h stores complete
        if (tid == 0) st_flag(&flags[blk * FSTR], (unsigned)(step + 2));
    }
}

// ---------------- projection GEMM: C[4096][32000] = g @ Wb^T + bias ----------------
__global__ __launch_bounds__(256)
void gemm_kernel(const __hip_bfloat16* __restrict__ A, const __hip_bfloat16* __restrict__ Bw,
                 const float* __restrict__ bias, float* __restrict__ C) {
    __shared__ alignas(16) unsigned short As[128][72];
    __shared__ alignas(16) unsigned short Bs[128][72];
    const int tid = threadIdx.x;
    // bijective XCD-chunked swizzle: 8000 blocks = 8 XCDs x 1000
    const int bid = blockIdx.x;
    const int co = (bid & 7) * 1000 + (bid >> 3);
    const int bm = co & 31, bn = co >> 5;
    const int rowbase = bm * 128, colbase = bn * 128;
    const int lane = tid & 63, w = tid >> 6;
    const int wm = w >> 1, wn = w & 1;
    const int lr = lane & 15, lkg = lane >> 4;

    f32x4 acc[4][4];
    #pragma unroll
    for (int i = 0; i < 4; ++i)
        #pragma unroll
        for (int j = 0; j < 4; ++j) acc[i][j] = (f32x4){0.f, 0.f, 0.f, 0.f};

    const int srow = tid >> 3, skk = (tid & 7) * 8;

    for (int kt = 0; kt < 11; ++kt) {
        const int k0 = kt * 64;
        __syncthreads();
        #pragma unroll
        for (int i = 0; i < 4; ++i) {
            int r = srow + i * 32;
            *(uint4*)&As[r][skk] = *(const uint4*)&A[(size_t)(rowbase + r) * KP + k0 + skk];
            *(uint4*)&Bs[r][skk] = *(const uint4*)&Bw[(size_t)(colbase + r) * KP + k0 + skk];
        }
        __syncthreads();
        #pragma unroll
        for (int ks = 0; ks < 2; ++ks) {
            bf16x8 af[4], bf[4];
            #pragma unroll
            for (int i = 0; i < 4; ++i)
                af[i] = *(const bf16x8*)&As[wm * 64 + i * 16 + lr][ks * 32 + lkg * 8];
            #pragma unroll
            for (int j = 0; j < 4; ++j)
                bf[j] = *(const bf16x8*)&Bs[wn * 64 + j * 16 + lr][ks * 32 + lkg * 8];
            #pragma unroll
            for (int i = 0; i < 4; ++i)
                #pragma unroll
                for (int j = 0; j < 4; ++j)
                    acc[i][j] = __builtin_amdgcn_mfma_f32_16x16x32_bf16(af[i], bf[j], acc[i][j], 0, 0, 0);
        }
    }

    float bv[4];
    #pragma unroll
    for (int j = 0; j < 4; ++j) bv[j] = bias[colbase + wn * 64 + j * 16 + lr];
    #pragma unroll
    for (int i = 0; i < 4; ++i) {
        int grow0 = rowbase + wm * 64 + i * 16 + lkg * 4;
        #pragma unroll
        for (int j = 0; j < 4; ++j) {
            int gcol = colbase + wn * 64 + j * 16 + lr;
            #pragma unroll
            for (int r = 0; r < 4; ++r)
                C[(size_t)(grow0 + r) * V_ + gcol] = acc[i][j][r] + bv[j];
        }
    }
}

extern "C" void kernel_launch(void* const* d_in, const int* in_sizes, int n_in,
                              void* d_out, int out_size, void* d_ws, size_t ws_size,
                              hipStream_t stream) {
    const float* labels = (const float*)d_in[0];
    const float* z      = (const float*)d_in[1];
    const int*   di     = (const int*)d_in[2];
    const float* mask   = (const float*)d_in[3];
    const float* emb    = (const float*)d_in[4];
    const float* W1     = (const float*)d_in[5];
    const float* b1     = (const float*)d_in[6];
    const float* g1k    = (const float*)d_in[7];
    const float* g1rk   = (const float*)d_in[8];
    const float* g1b    = (const float*)d_in[9];
    const float* pW     = (const float*)d_in[10];
    const float* pb     = (const float*)d_in[11];

    // ws: long-lived buffers (~51 MB)
    char* ws = (char*)d_ws;
    __hip_bfloat16* g    = (__hip_bfloat16*)ws;                    //  5,767,168 B
    __hip_bfloat16* Wb   = (__hip_bfloat16*)(ws + 5767168);        // 45,056,000 B
    unsigned short* hhi  = (unsigned short*)(ws + 50823168);       //     98,304 B
    unsigned short* hlo  = (unsigned short*)(ws + 50921472);       //     98,304 B
    unsigned*       flags= (unsigned*)(ws + 51019776);             //     11,200 B

    // d_out doubles as scratch for GRU-phase-only data (dead before gemm writes C)
    char* ob = (char*)d_out;
    float*          xpt  = (float*)ob;                             // 34,406,400 B
    __hip_bfloat16* mkt  = (__hip_bfloat16*)(ob + 34406400);       //  5,734,400 B
    float*          xp   = (float*)(ob + 40140800);                // 34,406,400 B

    hipMemsetAsync(flags, 0, NBLK * FSTR * sizeof(unsigned), stream);

    wconv_kernel<<<dim3(1000, 22), dim3(32, 8), 0, stream>>>(pW, Wb);
    xp_kernel<<<dim3(4096), 256, 0, stream>>>(di, emb, g1k, g1b, xp, g);
    xpt_kernel<<<dim3(66, 128), dim3(32, 8), 0, stream>>>(xp, xpt);
    maskt_kernel<<<dim3(22, 128), dim3(32, 8), 0, stream>>>(mask, mkt);

    gru_kernel<<<dim3(NBLK), 256, 0, stream>>>(labels, z, W1, b1, xpt, mkt,
                                               g1rk, g1b, hhi, hlo, g, flags);

    gemm_kernel<<<dim3(8000), 256, 0, stream>>>(g, Wb, pb, (float*)d_out);
}